// Round 1
// baseline (227.623 us; speedup 1.0000x reference)
//
#include <hip/hip_runtime.h>

#define B_SZ 128
#define IN_CAPS 1152
#define IN_DIM 8
#define N_CAPS 16
#define DIM 16

#define I_PER_BLK 16
#define B_PER_BLK 16
#define ICN (IN_CAPS / I_PER_BLK)   // 72
#define BTN (B_SZ / B_PER_BLK)      // 8
#define SLICE (B_SZ * N_CAPS * DIM) // 32768 floats per partial slice

// One routing pass, fused: recompute hat[b,n,i,e] on the fly (W register-resident),
// compute routing logits from prev outputs, in-wave softmax over n, partial-sum s
// over this block's 16 i's, write deterministic partial[ic][b][n][e].
// thread tid -> i_sub = tid>>4 (0..15), n = tid&15. One wave = 4 i_subs x 16 n.
template<bool ROUTED>
__global__ __launch_bounds__(256, 2)
void caps_pass(const float* __restrict__ x, const float* __restrict__ W,
               const float* __restrict__ prev, float* __restrict__ partial)
{
    const int tid   = threadIdx.x;
    const int i_sub = tid >> 4;
    const int n     = tid & 15;
    const int ic    = blockIdx.x;          // 0..71
    const int bt    = blockIdx.y;          // 0..7
    const int i     = ic * I_PER_BLK + i_sub;
    const int b0    = bt * B_PER_BLK;

    __shared__ float red[4][16][16];       // [wave][n][e]

    // W[n][i][e][d] -> 128 VGPRs, reused across all 16 b's of this block.
    float Wreg[16][8];
    {
        const float4* wp = (const float4*)(W + (((size_t)n * IN_CAPS + i) << 7));
        #pragma unroll
        for (int e = 0; e < 16; ++e) {
            float4 a = wp[2 * e], b4 = wp[2 * e + 1];
            Wreg[e][0] = a.x;  Wreg[e][1] = a.y;  Wreg[e][2] = a.z;  Wreg[e][3] = a.w;
            Wreg[e][4] = b4.x; Wreg[e][5] = b4.y; Wreg[e][6] = b4.z; Wreg[e][7] = b4.w;
        }
    }

    for (int bs = 0; bs < B_PER_BLK; ++bs) {
        const int b = b0 + bs;

        // x[b][i][0:8] — 32B row, shared by the 16 lanes of this i_sub (L1 broadcast)
        const float4* xp = (const float4*)(x + ((size_t)b * IN_CAPS + i) * IN_DIM);
        float4 x0 = xp[0], x1 = xp[1];
        float xr[8] = {x0.x, x0.y, x0.z, x0.w, x1.x, x1.y, x1.z, x1.w};

        // hat[e] = sum_d x[b,i,d] * W[n,i,e,d]  (128 FMA, all register operands)
        float hat[16];
        #pragma unroll
        for (int e = 0; e < 16; ++e) {
            float h = 0.f;
            #pragma unroll
            for (int d = 0; d < 8; ++d) h = fmaf(xr[d], Wreg[e][d], h);
            hat[e] = h;
        }

        float c;
        if (ROUTED) {
            // logit = dot(prev[b,n,:], hat[:])   (prev = out0 or out0+out1)
            const float4* op = (const float4*)(prev + ((size_t)b * N_CAPS + n) * DIM);
            float logit = 0.f;
            #pragma unroll
            for (int q = 0; q < 4; ++q) {
                float4 o = op[q];
                logit = fmaf(o.x, hat[4 * q + 0], logit);
                logit = fmaf(o.y, hat[4 * q + 1], logit);
                logit = fmaf(o.z, hat[4 * q + 2], logit);
                logit = fmaf(o.w, hat[4 * q + 3], logit);
            }
            // softmax over n: 16 contiguous lanes, pure in-wave shuffles
            float m = logit;
            #pragma unroll
            for (int msk = 8; msk >= 1; msk >>= 1)
                m = fmaxf(m, __shfl_xor(m, msk));
            float p = __expf(logit - m);
            float Z = p;
            #pragma unroll
            for (int msk = 8; msk >= 1; msk >>= 1)
                Z += __shfl_xor(Z, msk);
            c = p / Z;
        } else {
            c = 1.0f / 16.0f;  // softmax of all-zero logits
        }

        // r[e] = sum over this wave's 4 i_subs of c*hat[e]
        float r[16];
        #pragma unroll
        for (int e = 0; e < 16; ++e) {
            float v = c * hat[e];
            v += __shfl_xor(v, 16);
            v += __shfl_xor(v, 32);
            r[e] = v;
        }

        const int lane = tid & 63;
        const int w    = tid >> 6;
        if (lane < 16) {
            #pragma unroll
            for (int e = 0; e < 16; ++e) red[w][lane][e] = r[e];
        }
        __syncthreads();
        {
            // thread tid -> (nn = tid>>4, ee = tid&15); coalesced 1KB store
            const int nn = tid >> 4, ee = tid & 15;
            float s = red[0][nn][ee] + red[1][nn][ee] + red[2][nn][ee] + red[3][nn][ee];
            partial[(size_t)ic * SLICE + ((size_t)b << 8) + tid] = s;
        }
        __syncthreads();
    }
}

// Sum partials over 72 i-chunks, add B, squash over e (16-lane shuffle).
// MODE 0: prevbuf = out0;  MODE 1: prevbuf += out1 (-> out0+out1);  MODE 2: d_out = final.
template<int MODE>
__global__ __launch_bounds__(256)
void caps_squash(const float* __restrict__ partial, const float* __restrict__ Bb,
                 float* __restrict__ prevbuf, float* __restrict__ out)
{
    const int g = blockIdx.x * 256 + threadIdx.x;  // g = b*256 + n*16 + e
    float s = 0.f;
    #pragma unroll 8
    for (int ic = 0; ic < ICN; ++ic)
        s += partial[(size_t)ic * SLICE + g];
    s += Bb[g & 255];

    float s2 = s * s;
    #pragma unroll
    for (int msk = 8; msk >= 1; msk >>= 1)
        s2 += __shfl_xor(s2, msk);

    // squash scale = s2/(1+s2)/sqrt(s2) = sqrt(s2)/(1+s2)
    float v = s * (sqrtf(s2) / (1.0f + s2));

    if (MODE == 0)      prevbuf[g] = v;
    else if (MODE == 1) prevbuf[g] = prevbuf[g] + v;
    else                out[g] = v;
}

extern "C" void kernel_launch(void* const* d_in, const int* in_sizes, int n_in,
                              void* d_out, int out_size, void* d_ws, size_t ws_size,
                              hipStream_t stream)
{
    const float* x  = (const float*)d_in[0];   // [128,1152,8]
    const float* W  = (const float*)d_in[1];   // [16,1152,16,8]
    const float* Bb = (const float*)d_in[2];   // [16,16]
    float* out = (float*)d_out;                // [128,16,16]

    float* prevbuf = (float*)d_ws;             // 32768 floats (out0, then out0+out1)
    float* partial = prevbuf + SLICE;          // 72 * 32768 floats (9.4 MB)

    dim3 pg(ICN, BTN);  // 72 x 8 = 576 blocks

    // iter 0: c uniform
    caps_pass<false><<<pg, 256, 0, stream>>>(x, W, nullptr, partial);
    caps_squash<0><<<SLICE / 256, 256, 0, stream>>>(partial, Bb, prevbuf, nullptr);
    // iter 1: logits = dot(out0, hat)
    caps_pass<true><<<pg, 256, 0, stream>>>(x, W, prevbuf, partial);
    caps_squash<1><<<SLICE / 256, 256, 0, stream>>>(partial, Bb, prevbuf, nullptr);
    // iter 2: logits = dot(out0+out1, hat)
    caps_pass<true><<<pg, 256, 0, stream>>>(x, W, prevbuf, partial);
    caps_squash<2><<<SLICE / 256, 256, 0, stream>>>(partial, Bb, prevbuf, out);
}

// Round 2
// 223.432 us; speedup vs baseline: 1.0188x; 1.0188x over previous
//
#include <hip/hip_runtime.h>

#define B_SZ 128
#define IN_CAPS 1152
#define IN_DIM 8
#define N_CAPS 16
#define DIM 16

#define I_PER_BLK 16
#define B_PER_BLK 16
#define ICN (IN_CAPS / I_PER_BLK)   // 72
#define BTN (B_SZ / B_PER_BLK)      // 8
#define SLICE (B_SZ * N_CAPS * DIM) // 32768 floats per partial slice

// One routing pass, fused: recompute hat[b,n,i,e] on the fly (W register-resident),
// compute routing logits from prev outputs, in-wave softmax over n, partial-sum s
// over this block's 16 i's, write deterministic partial[ic][b][n][e].
// thread tid -> i_sub = tid>>4 (0..15), n = tid&15. One wave = 4 i_subs x 16 n.
// waves_per_eu(2,2): pin occupancy to exactly 2 waves/EU -> 256-VGPR budget so the
// 128-float Wreg stays in registers (R1: default heuristic spilled it, VGPR=96, 60us).
template<bool ROUTED>
__global__ __launch_bounds__(256) __attribute__((amdgpu_waves_per_eu(2, 2)))
void caps_pass(const float* __restrict__ x, const float* __restrict__ W,
               const float* __restrict__ prev, float* __restrict__ partial)
{
    const int tid   = threadIdx.x;
    const int i_sub = tid >> 4;
    const int n     = tid & 15;
    const int ic    = blockIdx.x;          // 0..71
    const int bt    = blockIdx.y;          // 0..7
    const int i     = ic * I_PER_BLK + i_sub;
    const int b0    = bt * B_PER_BLK;

    __shared__ float red[4][16][17];       // [wave][n][e] (+1 pad: 17l%32 distinct -> conflict-free)

    // W[n][i][e][d] -> 128 VGPRs, reused across all 16 b's of this block.
    float Wreg[16][8];
    {
        const float4* wp = (const float4*)(W + (((size_t)n * IN_CAPS + i) << 7));
        #pragma unroll
        for (int e = 0; e < 16; ++e) {
            float4 a = wp[2 * e], b4 = wp[2 * e + 1];
            Wreg[e][0] = a.x;  Wreg[e][1] = a.y;  Wreg[e][2] = a.z;  Wreg[e][3] = a.w;
            Wreg[e][4] = b4.x; Wreg[e][5] = b4.y; Wreg[e][6] = b4.z; Wreg[e][7] = b4.w;
        }
    }

    for (int bs = 0; bs < B_PER_BLK; ++bs) {
        const int b = b0 + bs;

        // x[b][i][0:8] — 32B row, shared by the 16 lanes of this i_sub (L1 broadcast)
        const float4* xp = (const float4*)(x + ((size_t)b * IN_CAPS + i) * IN_DIM);
        float4 x0 = xp[0], x1 = xp[1];
        float xr[8] = {x0.x, x0.y, x0.z, x0.w, x1.x, x1.y, x1.z, x1.w};

        // hat[e] = sum_d x[b,i,d] * W[n,i,e,d]  (128 FMA, all register operands)
        float hat[16];
        #pragma unroll
        for (int e = 0; e < 16; ++e) {
            float h = 0.f;
            #pragma unroll
            for (int d = 0; d < 8; ++d) h = fmaf(xr[d], Wreg[e][d], h);
            hat[e] = h;
        }

        float c;
        if (ROUTED) {
            // logit = dot(prev[b,n,:], hat[:])   (prev = out0 or out0+out1)
            const float4* op = (const float4*)(prev + ((size_t)b * N_CAPS + n) * DIM);
            float logit = 0.f;
            #pragma unroll
            for (int q = 0; q < 4; ++q) {
                float4 o = op[q];
                logit = fmaf(o.x, hat[4 * q + 0], logit);
                logit = fmaf(o.y, hat[4 * q + 1], logit);
                logit = fmaf(o.z, hat[4 * q + 2], logit);
                logit = fmaf(o.w, hat[4 * q + 3], logit);
            }
            // softmax over n: 16 contiguous lanes, pure in-wave shuffles
            float m = logit;
            #pragma unroll
            for (int msk = 8; msk >= 1; msk >>= 1)
                m = fmaxf(m, __shfl_xor(m, msk));
            float p = __expf(logit - m);
            float Z = p;
            #pragma unroll
            for (int msk = 8; msk >= 1; msk >>= 1)
                Z += __shfl_xor(Z, msk);
            c = p / Z;
        } else {
            c = 1.0f / 16.0f;  // softmax of all-zero logits
        }

        // r[e] = sum over this wave's 4 i_subs of c*hat[e]
        float r[16];
        #pragma unroll
        for (int e = 0; e < 16; ++e) {
            float v = c * hat[e];
            v += __shfl_xor(v, 16);
            v += __shfl_xor(v, 32);
            r[e] = v;
        }

        const int lane = tid & 63;
        const int w    = tid >> 6;
        if (lane < 16) {
            #pragma unroll
            for (int e = 0; e < 16; ++e) red[w][lane][e] = r[e];
        }
        __syncthreads();
        {
            // thread tid -> (nn = tid>>4, ee = tid&15); coalesced 1KB store
            const int nn = tid >> 4, ee = tid & 15;
            float s = red[0][nn][ee] + red[1][nn][ee] + red[2][nn][ee] + red[3][nn][ee];
            partial[(size_t)ic * SLICE + ((size_t)b << 8) + tid] = s;
        }
        __syncthreads();
    }
}

// Sum partials over 72 i-chunks, add B, squash over e (16-lane shuffle).
// Grid: 512 blocks x 256 threads. Block handles 64 g's; 4 threads per g split the
// 72-slice sum (18 each) -> LDS combine -> wave 0 squashes & writes.
// MODE 0: prevbuf = out0;  MODE 1: prevbuf += out1 (-> out0+out1);  MODE 2: d_out = final.
template<int MODE>
__global__ __launch_bounds__(256)
void caps_squash(const float* __restrict__ partial, const float* __restrict__ Bb,
                 float* __restrict__ prevbuf, float* __restrict__ out)
{
    const int tid   = threadIdx.x;
    const int g_sub = tid & 63;
    const int icg   = tid >> 6;            // 0..3
    const int g0    = blockIdx.x * 64;     // 512 blocks x 64 g
    const int g     = g0 + g_sub;

    float s = 0.f;
    #pragma unroll
    for (int k = 0; k < 18; ++k)
        s += partial[(size_t)(icg * 18 + k) * SLICE + g];

    __shared__ float sums[4][64];
    sums[icg][g_sub] = s;
    __syncthreads();

    if (tid < 64) {
        float t = sums[0][g_sub] + sums[1][g_sub] + sums[2][g_sub] + sums[3][g_sub];
        t += Bb[g & 255];

        // squash: e = low 4 bits of lane (g = b*256 + n*16 + e)
        float s2 = t * t;
        #pragma unroll
        for (int msk = 8; msk >= 1; msk >>= 1)
            s2 += __shfl_xor(s2, msk);
        float v = t * (sqrtf(s2) / (1.0f + s2));

        if (MODE == 0)      prevbuf[g] = v;
        else if (MODE == 1) prevbuf[g] = prevbuf[g] + v;
        else                out[g] = v;
    }
}

extern "C" void kernel_launch(void* const* d_in, const int* in_sizes, int n_in,
                              void* d_out, int out_size, void* d_ws, size_t ws_size,
                              hipStream_t stream)
{
    const float* x  = (const float*)d_in[0];   // [128,1152,8]
    const float* W  = (const float*)d_in[1];   // [16,1152,16,8]
    const float* Bb = (const float*)d_in[2];   // [16,16]
    float* out = (float*)d_out;                // [128,16,16]

    float* prevbuf = (float*)d_ws;             // 32768 floats (out0, then out0+out1)
    float* partial = prevbuf + SLICE;          // 72 * 32768 floats (9.4 MB)

    dim3 pg(ICN, BTN);  // 72 x 8 = 576 blocks

    // iter 0: c uniform
    caps_pass<false><<<pg, 256, 0, stream>>>(x, W, nullptr, partial);
    caps_squash<0><<<SLICE / 64, 256, 0, stream>>>(partial, Bb, prevbuf, nullptr);
    // iter 1: logits = dot(out0, hat)
    caps_pass<true><<<pg, 256, 0, stream>>>(x, W, prevbuf, partial);
    caps_squash<1><<<SLICE / 64, 256, 0, stream>>>(partial, Bb, prevbuf, nullptr);
    // iter 2: logits = dot(out0+out1, hat)
    caps_pass<true><<<pg, 256, 0, stream>>>(x, W, prevbuf, partial);
    caps_squash<2><<<SLICE / 64, 256, 0, stream>>>(partial, Bb, prevbuf, out);
}